// Round 1
// baseline (2483.006 us; speedup 1.0000x reference)
//
#include <hip/hip_runtime.h>
#include <math.h>

#define T_STEPS 4096
#define B_N     512

// 20 floats = 80 bytes, five float4 loads per (t,b) step.
struct alignas(16) Pk {
  float KU1, KU2, KU3, KU4;   // kp*u_i/tau2^2
  float A,   mn,  mx,  cthr;  // A=-2*damp*tau2 ; cthr = tau*kTh/mB
  float cdym, cdxm, cq, cdx;  // tau*kTh*dym/IBxx ; tau*kTh*dxm/IByy ; tau*kTo/IBzz ; tau*Cd/mB
  float cA,  cB,  cC,  cD;    // tau*(IByy-IBzz)/IBxx ; tau*uP*IRzz/IBxx ; tau*(IBzz-IBxx)/IByy ; tau*uP*IRzz/IByy
  float cE,  label, pad0, pad1; // tau*(IBxx-IByy)/IBzz
};

union PkU { Pk p; float4 v[5]; };

__device__ __forceinline__ float sc_ref(float g, float base) {
  // reference: (1 + (0.5-g)*0.95) * base  (keep ref association)
  return (1.0f + (0.5f - g) * 0.95f) * base;
}

__device__ __forceinline__ Pk computePk(size_t i,
    const float* __restrict__ logits,
    const float* __restrict__ u1, const float* __restrict__ u2,
    const float* __restrict__ u3, const float* __restrict__ u4,
    const float* __restrict__ mxM, const float* __restrict__ mnM,
    const float* __restrict__ labels) {
  const float4* lg = (const float4*)logits + i * 3;
  float4 l0 = lg[0], l1 = lg[1], l2 = lg[2];
  // logits lanes: g0..g11 ; g2 unused by reference
  float dxm  = sc_ref(l0.x, 0.16f);
  float dym  = sc_ref(l0.y, 0.16f);
  float IBxx = sc_ref(l0.w, 0.0123f);
  float IByy = sc_ref(l1.x, 0.0123f);
  float IBzz = sc_ref(l1.y, 0.0123f);
  float Cd   = sc_ref(l1.z, 0.1f);
  float kTh  = sc_ref(l1.w, 1.076e-05f);
  float kTo  = sc_ref(l2.x, 1.632e-07f);
  float tau2 = sc_ref(l2.y, 0.015f);
  float kp   = sc_ref(l2.z, 1.0f);
  float damp = sc_ref(l2.w, 1.0f);
  const float tau = 0.005f;
  const float tauOverMb = tau / 1.2f;
  Pk p;
  float K = kp / (tau2 * tau2);
  p.KU1 = K * u1[i];  p.KU2 = K * u2[i];  p.KU3 = K * u3[i];  p.KU4 = K * u4[i];
  p.A   = -2.0f * damp * tau2;
  p.mn  = mnM[i];  p.mx = mxM[i];
  p.cthr = kTh * tauOverMb;
  float tx = tau / IBxx, ty = tau / IByy, tz = tau / IBzz;
  p.cdym = kTh * dym * tx;
  p.cdxm = kTh * dxm * ty;
  p.cq   = kTo * tz;
  p.cdx  = Cd * tauOverMb;
  p.cA = (IByy - IBzz) * tx;
  p.cB = 1e-04f * tx;          // uP*IRzz = 1.0*1e-4
  p.cC = (IBzz - IBxx) * ty;
  p.cD = 1e-04f * ty;
  p.cE = (IBxx - IByy) * tz;
  p.label = labels[i];
  p.pad0 = 0.f; p.pad1 = 0.f;
  return p;
}

// Live state (xx, xy, xd, yd eliminated: they never feed the z chain)
struct Carry {
  float xz, q0, q1, q2, q3, zd, pv, qv, rv;
  float w1, w2, w3, w4, wd1, wd2, wd3, wd4;
};

__device__ __forceinline__ void stepOne(Carry& c, const Pk& p, double& acc) {
  const float TAU = 0.005f, HTAU = 0.0025f, TAUG = 0.04905f; // tau*g
  // motor accel (uses UNCLIPPED carry w)
  float wdd1 = fmaf(p.A, c.wd1, p.KU1) - c.w1;
  float wdd2 = fmaf(p.A, c.wd2, p.KU2) - c.w2;
  float wdd3 = fmaf(p.A, c.wd3, p.KU3) - c.w3;
  float wdd4 = fmaf(p.A, c.wd4, p.KU4) - c.w4;
  // clipped motors for thrust and nw
  float w1c = fminf(fmaxf(c.w1, p.mn), p.mx);
  float w2c = fminf(fmaxf(c.w2, p.mn), p.mx);
  float w3c = fminf(fmaxf(c.w3, p.mn), p.mx);
  float w4c = fminf(fmaxf(c.w4, p.mn), p.mx);
  float s1 = w1c * w1c, s2 = w2c * w2c, s3 = w3c * w3c, s4 = w4c * w4c;
  float sA = s1 + s3, sB = s2 + s4;
  float ssum = sA + sB;
  float dymd = (s1 + s4) - (s2 + s3);   // s1-s2-s3+s4
  float dxmd = (s1 + s2) - (s3 + s4);   // s1+s2-s3-s4
  float dqd  = sB - sA;                 // -s1+s2-s3+s4
  float Thr2 = p.cthr * ssum;           // tau*Thr/mB
  float qq = fmaf(c.q0, c.q0, c.q3 * c.q3) - fmaf(c.q1, c.q1, c.q2 * c.q2);
  float zdm = c.zd * fabsf(c.zd);       // sign(zd)*zd^2
  float nzd = fmaf(-p.cdx, zdm, c.zd);
  nzd = fmaf(Thr2, qq, nzd) - TAUG;
  // quaternion derivative
  float t0 = fmaf(c.pv, c.q1, fmaf(c.qv, c.q2,  c.rv * c.q3));
  float t1 = fmaf(c.pv, c.q0, fmaf(-c.qv, c.q3, c.rv * c.q2));
  float t2 = fmaf(c.pv, c.q3, fmaf(c.qv, c.q0, -(c.rv * c.q1)));
  float t3 = fmaf(-c.pv, c.q2, fmaf(c.qv, c.q1, c.rv * c.q0));
  float nq0 = fmaf(-HTAU, t0, c.q0);
  float nq1 = fmaf( HTAU, t1, c.q1);
  float nq2 = fmaf( HTAU, t2, c.q2);
  float nq3 = fmaf( HTAU, t3, c.q3);
  // body rates
  float wsum = (w1c - w2c) + (w3c - w4c);
  float npv = fmaf(p.cA, c.qv * c.rv, c.pv);
  npv = fmaf(-p.cB, wsum * c.qv, npv);
  npv = fmaf(p.cdym, dymd, npv);
  float nqv = fmaf(p.cC, c.pv * c.rv, c.qv);
  nqv = fmaf(p.cD, wsum * c.pv, nqv);
  nqv = fmaf(p.cdxm, dxmd, nqv);
  float nrv = fmaf(p.cE, c.pv * c.qv, c.rv);
  nrv = fmaf(p.cq, dqd, nrv);
  // z update + mask (bit-level finite check: robust to any fast-math)
  float nxz = fmaf(TAU, nzd, c.xz);
  float d = nxz - c.xz;
  unsigned eb = (__float_as_uint(nxz) >> 23) & 0xFFu;
  bool ok = (fabsf(d) <= 400.0f) & (eb != 0xFFu);
  float xznew = ok ? nxz : c.xz;
  // loss accumulate (f64)
  float e = xznew - p.label;
  acc = fma((double)e, (double)e, acc);
  // commit (nw uses OLD wd; nwd uses wdd)
  c.w1 = fmaf(TAU, c.wd1, w1c);
  c.w2 = fmaf(TAU, c.wd2, w2c);
  c.w3 = fmaf(TAU, c.wd3, w3c);
  c.w4 = fmaf(TAU, c.wd4, w4c);
  c.wd1 = fmaf(TAU, wdd1, c.wd1);
  c.wd2 = fmaf(TAU, wdd2, c.wd2);
  c.wd3 = fmaf(TAU, wdd3, c.wd3);
  c.wd4 = fmaf(TAU, wdd4, c.wd4);
  c.q0 = nq0; c.q1 = nq1; c.q2 = nq2; c.q3 = nq3;
  c.pv = npv; c.qv = nqv; c.rv = nrv;
  c.zd = nzd; c.xz = xznew;
}

// ---- kernel 1: partial sums of kTh over T*B (deterministic tree) ----
__global__ void k_kth(const float* __restrict__ logits, float* __restrict__ partial) {
  __shared__ float sm[256];
  float a = 0.f;
  const int n = T_STEPS * B_N;
  for (int i = blockIdx.x * 256 + threadIdx.x; i < n; i += 1024 * 256)
    a += (1.0f + (0.5f - logits[(size_t)i * 12 + 7]) * 0.95f) * 1.076e-05f;
  sm[threadIdx.x] = a; __syncthreads();
  for (int s = 128; s; s >>= 1) {
    if (threadIdx.x < s) sm[threadIdx.x] += sm[threadIdx.x + s];
    __syncthreads();
  }
  if (threadIdx.x == 0) partial[blockIdx.x] = sm[0];
}

// ---- kernel 2: finalize hover ----
__global__ void k_hover(const float* __restrict__ partial, float* __restrict__ hover) {
  __shared__ float sm[1024];
  sm[threadIdx.x] = partial[threadIdx.x];
  __syncthreads();
  for (int s = 512; s; s >>= 1) {
    if (threadIdx.x < s) sm[threadIdx.x] += sm[threadIdx.x + s];
    __syncthreads();
  }
  if (threadIdx.x == 0) {
    float mean = sm[0] * (1.0f / 2097152.0f);
    float h = 1.2f * 9.81f / (4.0f * mean + 1e-12f);
    hover[0] = sqrtf(fmaxf(h, 1e-06f));
  }
}

// ---- kernel 3: per-(t,b) parameter precompute (fully parallel) ----
__global__ void k_pre(const float* __restrict__ logits,
                      const float* __restrict__ u1, const float* __restrict__ u2,
                      const float* __restrict__ u3, const float* __restrict__ u4,
                      const float* __restrict__ mxM, const float* __restrict__ mnM,
                      const float* __restrict__ labels, Pk* __restrict__ pack) {
  size_t i = (size_t)blockIdx.x * 256 + threadIdx.x;  // 8192*256 == T*B exactly
  PkU u;
  u.p = computePk(i, logits, u1, u2, u3, u4, mxM, mnM, labels);
  float4* dst = (float4*)(pack + i);
  #pragma unroll
  for (int k = 0; k < 5; ++k) dst[k] = u.v[k];
}

// ---- kernel 4: the serial scan, one thread per batch column ----
template<int MODE>  // 1: packed params from ws ; 0: inline compute
__global__ __launch_bounds__(64, 1) void k_sim(
    const Pk* __restrict__ pack,
    const float* __restrict__ logits,
    const float* __restrict__ u1, const float* __restrict__ u2,
    const float* __restrict__ u3, const float* __restrict__ u4,
    const float* __restrict__ mxM, const float* __restrict__ mnM,
    const float* __restrict__ labels,
    const float* __restrict__ hoverp, double* __restrict__ bsum) {
  int b = blockIdx.x * 64 + threadIdx.x;
  float hv = hoverp[0];
  Carry c;
  c.xz = 0.f; c.q0 = 1.f; c.q1 = 0.f; c.q2 = 0.f; c.q3 = 0.f;
  c.zd = 0.f; c.pv = 0.f; c.qv = 0.f; c.rv = 0.f;
  c.w1 = hv; c.w2 = hv; c.w3 = hv; c.w4 = hv;
  c.wd1 = 0.f; c.wd2 = 0.f; c.wd3 = 0.f; c.wd4 = 0.f;
  // t=0 term: pred_z[0]=0 vs labels[0]
  float l0 = labels[b];
  double acc = (double)l0 * (double)l0;

  auto ld = [&](int t) -> Pk {
    size_t i = (size_t)t * B_N + b;
    if (MODE == 1) {
      PkU u;
      const float4* s = (const float4*)(pack + i);
      #pragma unroll
      for (int k = 0; k < 5; ++k) u.v[k] = s[k];
      return u.p;
    } else {
      return computePk(i, logits, u1, u2, u3, u4, mxM, mnM, labels);
    }
  };

  // 3-deep software pipeline; 4095 = 3*1365 iterations exactly
  Pk pa = ld(1), pb = ld(2), pc = ld(3);
  for (int t = 1; t + 2 < T_STEPS; t += 3) {
    stepOne(c, pa, acc); pa = ld(t + 3 < T_STEPS ? t + 3 : T_STEPS - 1);
    stepOne(c, pb, acc); pb = ld(t + 4 < T_STEPS ? t + 4 : T_STEPS - 1);
    stepOne(c, pc, acc); pc = ld(t + 5 < T_STEPS ? t + 5 : T_STEPS - 1);
  }
  bsum[b] = acc;
}

// ---- kernel 5: final deterministic reduce of 512 per-b sums ----
__global__ void k_final(const double* __restrict__ bsum, float* __restrict__ out) {
  __shared__ double sm[512];
  sm[threadIdx.x] = bsum[threadIdx.x];
  __syncthreads();
  for (int s = 256; s; s >>= 1) {
    if (threadIdx.x < s) sm[threadIdx.x] += sm[threadIdx.x + s];
    __syncthreads();
  }
  if (threadIdx.x == 0) out[0] = (float)(sm[0] * (1.0 / 2097152.0));
}

extern "C" void kernel_launch(void* const* d_in, const int* in_sizes, int n_in,
                              void* d_out, int out_size, void* d_ws, size_t ws_size,
                              hipStream_t stream) {
  // setup_inputs order: labels, logits, uMotor1..4, maxMotor, minMotor
  const float* labels = (const float*)d_in[0];
  const float* logits = (const float*)d_in[1];
  const float* u1 = (const float*)d_in[2];
  const float* u2 = (const float*)d_in[3];
  const float* u3 = (const float*)d_in[4];
  const float* u4 = (const float*)d_in[5];
  const float* mxM = (const float*)d_in[6];  // maxMotor
  const float* mnM = (const float*)d_in[7];  // minMotor
  float* out = (float*)d_out;

  char* ws = (char*)d_ws;
  float*  hover   = (float*)(ws);
  float*  partial = (float*)(ws + 256);
  double* bsum    = (double*)(ws + 8192);
  Pk*     pack    = (Pk*)(ws + 16384);
  size_t need = 16384 + (size_t)T_STEPS * B_N * sizeof(Pk);
  bool pre = (ws_size >= need);

  k_kth  <<<1024, 256, 0, stream>>>(logits, partial);
  k_hover<<<1, 1024, 0, stream>>>(partial, hover);
  if (pre) {
    k_pre<<<8192, 256, 0, stream>>>(logits, u1, u2, u3, u4, mxM, mnM, labels, pack);
    k_sim<1><<<8, 64, 0, stream>>>(pack, logits, u1, u2, u3, u4, mxM, mnM, labels, hover, bsum);
  } else {
    k_sim<0><<<8, 64, 0, stream>>>(nullptr, logits, u1, u2, u3, u4, mxM, mnM, labels, hover, bsum);
  }
  k_final<<<1, 512, 0, stream>>>(bsum, out);
}

// Round 3
// 1306.085 us; speedup vs baseline: 1.9011x; 1.9011x over previous
//
#include <hip/hip_runtime.h>
#include <math.h>

#define T_STEPS 4096
#define B_N     512
#define CHUNK   8
#define NCH     512   // 511*8+7 = 4095 steps; last chunk has 7 valid steps

// 20 floats = 80 bytes, five float4 loads per (t,b) step.
struct alignas(16) Pk {
  float KU1, KU2, KU3, KU4;   // kp*u_i/tau2^2
  float A,   mn,  mx,  cthr;  // A=-2*damp*tau2 ; cthr = tau*kTh/mB
  float cdym, cdxm, cq, cdx;  // tau*kTh*dym/IBxx ; tau*kTh*dxm/IByy ; tau*kTo/IBzz ; tau*Cd/mB
  float cA,  cB,  cC,  cD;    // tau*(IByy-IBzz)/IBxx ; tau*uP*IRzz/IBxx ; tau*(IBzz-IBxx)/IByy ; tau*uP*IRzz/IByy
  float cE,  label, pad0, pad1; // tau*(IBxx-IByy)/IBzz
};

union PkU { Pk p; float4 v[5]; };

__device__ __forceinline__ float sc_ref(float g, float base) {
  return (1.0f + (0.5f - g) * 0.95f) * base;
}

__device__ __forceinline__ Pk computePk(size_t i,
    const float* __restrict__ logits,
    const float* __restrict__ u1, const float* __restrict__ u2,
    const float* __restrict__ u3, const float* __restrict__ u4,
    const float* __restrict__ mxM, const float* __restrict__ mnM,
    const float* __restrict__ labels) {
  const float4* lg = (const float4*)logits + i * 3;
  float4 l0 = lg[0], l1 = lg[1], l2 = lg[2];
  float dxm  = sc_ref(l0.x, 0.16f);
  float dym  = sc_ref(l0.y, 0.16f);
  float IBxx = sc_ref(l0.w, 0.0123f);
  float IByy = sc_ref(l1.x, 0.0123f);
  float IBzz = sc_ref(l1.y, 0.0123f);
  float Cd   = sc_ref(l1.z, 0.1f);
  float kTh  = sc_ref(l1.w, 1.076e-05f);
  float kTo  = sc_ref(l2.x, 1.632e-07f);
  float tau2 = sc_ref(l2.y, 0.015f);
  float kp   = sc_ref(l2.z, 1.0f);
  float damp = sc_ref(l2.w, 1.0f);
  const float tau = 0.005f;
  const float tauOverMb = tau / 1.2f;
  Pk p;
  float K = kp / (tau2 * tau2);
  p.KU1 = K * u1[i];  p.KU2 = K * u2[i];  p.KU3 = K * u3[i];  p.KU4 = K * u4[i];
  p.A   = -2.0f * damp * tau2;
  p.mn  = mnM[i];  p.mx = mxM[i];
  p.cthr = kTh * tauOverMb;
  float tx = tau / IBxx, ty = tau / IByy, tz = tau / IBzz;
  p.cdym = kTh * dym * tx;
  p.cdxm = kTh * dxm * ty;
  p.cq   = kTo * tz;
  p.cdx  = Cd * tauOverMb;
  p.cA = (IByy - IBzz) * tx;
  p.cB = 1e-04f * tx;
  p.cC = (IBzz - IBxx) * ty;
  p.cD = 1e-04f * ty;
  p.cE = (IBxx - IByy) * tz;
  p.label = labels[i];
  p.pad0 = 0.f; p.pad1 = 0.f;
  return p;
}

struct Carry {
  float xz, q0, q1, q2, q3, zd, pv, qv, rv;
  float w1, w2, w3, w4, wd1, wd2, wd3, wd4;
};

__device__ __forceinline__ void stepOne(Carry& c, const Pk& p, double& acc) {
  const float TAU = 0.005f, HTAU = 0.0025f, TAUG = 0.04905f;
  float wdd1 = fmaf(p.A, c.wd1, p.KU1) - c.w1;
  float wdd2 = fmaf(p.A, c.wd2, p.KU2) - c.w2;
  float wdd3 = fmaf(p.A, c.wd3, p.KU3) - c.w3;
  float wdd4 = fmaf(p.A, c.wd4, p.KU4) - c.w4;
  float w1c = fminf(fmaxf(c.w1, p.mn), p.mx);
  float w2c = fminf(fmaxf(c.w2, p.mn), p.mx);
  float w3c = fminf(fmaxf(c.w3, p.mn), p.mx);
  float w4c = fminf(fmaxf(c.w4, p.mn), p.mx);
  float s1 = w1c * w1c, s2 = w2c * w2c, s3 = w3c * w3c, s4 = w4c * w4c;
  float sA = s1 + s3, sB = s2 + s4;
  float ssum = sA + sB;
  float dymd = (s1 + s4) - (s2 + s3);
  float dxmd = (s1 + s2) - (s3 + s4);
  float dqd  = sB - sA;
  float Thr2 = p.cthr * ssum;
  float qq = fmaf(c.q0, c.q0, c.q3 * c.q3) - fmaf(c.q1, c.q1, c.q2 * c.q2);
  float zdm = c.zd * fabsf(c.zd);
  float nzd = fmaf(-p.cdx, zdm, c.zd);
  nzd = fmaf(Thr2, qq, nzd) - TAUG;
  float t0 = fmaf(c.pv, c.q1, fmaf(c.qv, c.q2,  c.rv * c.q3));
  float t1 = fmaf(c.pv, c.q0, fmaf(-c.qv, c.q3, c.rv * c.q2));
  float t2 = fmaf(c.pv, c.q3, fmaf(c.qv, c.q0, -(c.rv * c.q1)));
  float t3 = fmaf(-c.pv, c.q2, fmaf(c.qv, c.q1, c.rv * c.q0));
  float nq0 = fmaf(-HTAU, t0, c.q0);
  float nq1 = fmaf( HTAU, t1, c.q1);
  float nq2 = fmaf( HTAU, t2, c.q2);
  float nq3 = fmaf( HTAU, t3, c.q3);
  float wsum = (w1c - w2c) + (w3c - w4c);
  float npv = fmaf(p.cA, c.qv * c.rv, c.pv);
  npv = fmaf(-p.cB, wsum * c.qv, npv);
  npv = fmaf(p.cdym, dymd, npv);
  float nqv = fmaf(p.cC, c.pv * c.rv, c.qv);
  nqv = fmaf(p.cD, wsum * c.pv, nqv);
  nqv = fmaf(p.cdxm, dxmd, nqv);
  float nrv = fmaf(p.cE, c.pv * c.qv, c.rv);
  nrv = fmaf(p.cq, dqd, nrv);
  float nxz = fmaf(TAU, nzd, c.xz);
  float d = nxz - c.xz;
  unsigned eb = (__float_as_uint(nxz) >> 23) & 0xFFu;
  bool ok = (fabsf(d) <= 400.0f) & (eb != 0xFFu);
  float xznew = ok ? nxz : c.xz;
  float e = xznew - p.label;
  acc = fma((double)e, (double)e, acc);
  c.w1 = fmaf(TAU, c.wd1, w1c);
  c.w2 = fmaf(TAU, c.wd2, w2c);
  c.w3 = fmaf(TAU, c.wd3, w3c);
  c.w4 = fmaf(TAU, c.wd4, w4c);
  c.wd1 = fmaf(TAU, wdd1, c.wd1);
  c.wd2 = fmaf(TAU, wdd2, c.wd2);
  c.wd3 = fmaf(TAU, wdd3, c.wd3);
  c.wd4 = fmaf(TAU, wdd4, c.wd4);
  c.q0 = nq0; c.q1 = nq1; c.q2 = nq2; c.q3 = nq3;
  c.pv = npv; c.qv = nqv; c.rv = nrv;
  c.zd = nzd; c.xz = xznew;
}

__device__ __forceinline__ void gload_lds16(const void* g, void* l) {
  __builtin_amdgcn_global_load_lds(
      (const __attribute__((address_space(1))) void*)g,
      (__attribute__((address_space(3))) void*)l, 16, 0, 0);
}

// ---- kernel 1: partial sums of kTh over T*B (deterministic tree) ----
__global__ void k_kth(const float* __restrict__ logits, float* __restrict__ partial) {
  __shared__ float sm[256];
  float a = 0.f;
  const int n = T_STEPS * B_N;
  for (int i = blockIdx.x * 256 + threadIdx.x; i < n; i += 1024 * 256)
    a += (1.0f + (0.5f - logits[(size_t)i * 12 + 7]) * 0.95f) * 1.076e-05f;
  sm[threadIdx.x] = a; __syncthreads();
  for (int s = 128; s; s >>= 1) {
    if (threadIdx.x < s) sm[threadIdx.x] += sm[threadIdx.x + s];
    __syncthreads();
  }
  if (threadIdx.x == 0) partial[blockIdx.x] = sm[0];
}

// ---- kernel 2: finalize hover ----
__global__ void k_hover(const float* __restrict__ partial, float* __restrict__ hover) {
  __shared__ float sm[1024];
  sm[threadIdx.x] = partial[threadIdx.x];
  __syncthreads();
  for (int s = 512; s; s >>= 1) {
    if (threadIdx.x < s) sm[threadIdx.x] += sm[threadIdx.x + s];
    __syncthreads();
  }
  if (threadIdx.x == 0) {
    float mean = sm[0] * (1.0f / 2097152.0f);
    float h = 1.2f * 9.81f / (4.0f * mean + 1e-12f);
    hover[0] = sqrtf(fmaxf(h, 1e-06f));
  }
}

// ---- kernel 3: per-(t,b) parameter precompute (fully parallel) ----
__global__ void k_pre(const float* __restrict__ logits,
                      const float* __restrict__ u1, const float* __restrict__ u2,
                      const float* __restrict__ u3, const float* __restrict__ u4,
                      const float* __restrict__ mxM, const float* __restrict__ mnM,
                      const float* __restrict__ labels, Pk* __restrict__ pack) {
  size_t i = (size_t)blockIdx.x * 256 + threadIdx.x;  // 8192*256 == T*B exactly
  PkU u;
  u.p = computePk(i, logits, u1, u2, u3, u4, mxM, mnM, labels);
  float4* dst = (float4*)(pack + i);
  #pragma unroll
  for (int k = 0; k < 5; ++k) dst[k] = u.v[k];
}

// ---- kernel 4: serial scan, LDS double-buffered async staging ----
__global__ __launch_bounds__(64, 1) void k_sim_lds(
    const Pk* __restrict__ pack,
    const float* __restrict__ labels,
    const float* __restrict__ hoverp, double* __restrict__ bsum) {
  __shared__ float4 lds[2][CHUNK][5][64];   // 80 KB
  const int lane = threadIdx.x;
  const int b = blockIdx.x * 64 + lane;
  float hv = hoverp[0];
  Carry c;
  c.xz = 0.f; c.q0 = 1.f; c.q1 = 0.f; c.q2 = 0.f; c.q3 = 0.f;
  c.zd = 0.f; c.pv = 0.f; c.qv = 0.f; c.rv = 0.f;
  c.w1 = hv; c.w2 = hv; c.w3 = hv; c.w4 = hv;
  c.wd1 = 0.f; c.wd2 = 0.f; c.wd3 = 0.f; c.wd4 = 0.f;
  float l0 = labels[b];
  double acc = (double)l0 * (double)l0;   // t=0 term: pred_z[0]=0

  const char* packb = (const char*)(pack + b);   // + t*B_N*80 per row

  auto stage = [&](int ch, int buf) {
    #pragma unroll
    for (int s = 0; s < CHUNK; ++s) {
      int t = 1 + ch * CHUNK + s;
      if (t > T_STEPS - 1) t = T_STEPS - 1;   // clamp (last chunk pad)
      const char* src = packb + (size_t)t * (B_N * sizeof(Pk));
      #pragma unroll
      for (int k = 0; k < 5; ++k)
        gload_lds16(src + 16 * k, (void*)&lds[buf][s][k][0]);
    }
  };

  stage(0, 0);   // prologue: chunk 0 -> buf 0 (40 loads in flight)

  PkU pA, pB;
  for (int ch = 0; ch < NCH; ++ch) {
    const int buf = ch & 1;
    if (ch + 1 < NCH) {
      stage(ch + 1, buf ^ 1);                          // 40 newer loads in flight
      asm volatile("s_waitcnt vmcnt(40)" ::: "memory"); // chunk `ch` resident
    } else {
      asm volatile("s_waitcnt vmcnt(0)" ::: "memory");
    }
    #pragma unroll
    for (int k = 0; k < 5; ++k) pA.v[k] = lds[buf][0][k][lane];
    #pragma unroll
    for (int s = 0; s < CHUNK; ++s) {
      PkU& curP = (s & 1) ? pB : pA;   // static: resolves at compile time
      PkU& nxtP = (s & 1) ? pA : pB;
      if (s + 1 < CHUNK) {             // prefetch next step into the spare set
        #pragma unroll
        for (int k = 0; k < 5; ++k) nxtP.v[k] = lds[buf][s + 1][k][lane];
      }
      int t = 1 + ch * CHUNK + s;
      if (t <= T_STEPS - 1)            // wave-uniform; only last chunk s=7 skips
        stepOne(c, curP.p, acc);
    }
  }
  bsum[b] = acc;
}

// ---- fallback (no workspace): inline params, no staging ----
__global__ __launch_bounds__(64, 1) void k_sim_fb(
    const float* __restrict__ logits,
    const float* __restrict__ u1, const float* __restrict__ u2,
    const float* __restrict__ u3, const float* __restrict__ u4,
    const float* __restrict__ mxM, const float* __restrict__ mnM,
    const float* __restrict__ labels,
    const float* __restrict__ hoverp, double* __restrict__ bsum) {
  int b = blockIdx.x * 64 + threadIdx.x;
  float hv = hoverp[0];
  Carry c;
  c.xz = 0.f; c.q0 = 1.f; c.q1 = 0.f; c.q2 = 0.f; c.q3 = 0.f;
  c.zd = 0.f; c.pv = 0.f; c.qv = 0.f; c.rv = 0.f;
  c.w1 = hv; c.w2 = hv; c.w3 = hv; c.w4 = hv;
  c.wd1 = 0.f; c.wd2 = 0.f; c.wd3 = 0.f; c.wd4 = 0.f;
  float l0 = labels[b];
  double acc = (double)l0 * (double)l0;
  for (int t = 1; t < T_STEPS; ++t) {
    Pk p = computePk((size_t)t * B_N + b, logits, u1, u2, u3, u4, mxM, mnM, labels);
    stepOne(c, p, acc);
  }
  bsum[b] = acc;
}

// ---- kernel 5: final deterministic reduce ----
__global__ void k_final(const double* __restrict__ bsum, float* __restrict__ out) {
  __shared__ double sm[512];
  sm[threadIdx.x] = bsum[threadIdx.x];
  __syncthreads();
  for (int s = 256; s; s >>= 1) {
    if (threadIdx.x < s) sm[threadIdx.x] += sm[threadIdx.x + s];
    __syncthreads();
  }
  if (threadIdx.x == 0) out[0] = (float)(sm[0] * (1.0 / 2097152.0));
}

extern "C" void kernel_launch(void* const* d_in, const int* in_sizes, int n_in,
                              void* d_out, int out_size, void* d_ws, size_t ws_size,
                              hipStream_t stream) {
  const float* labels = (const float*)d_in[0];
  const float* logits = (const float*)d_in[1];
  const float* u1 = (const float*)d_in[2];
  const float* u2 = (const float*)d_in[3];
  const float* u3 = (const float*)d_in[4];
  const float* u4 = (const float*)d_in[5];
  const float* mxM = (const float*)d_in[6];
  const float* mnM = (const float*)d_in[7];
  float* out = (float*)d_out;

  char* ws = (char*)d_ws;
  float*  hover   = (float*)(ws);
  float*  partial = (float*)(ws + 256);
  double* bsum    = (double*)(ws + 8192);
  Pk*     pack    = (Pk*)(ws + 16384);
  size_t need = 16384 + (size_t)T_STEPS * B_N * sizeof(Pk);
  bool pre = (ws_size >= need);

  k_kth  <<<1024, 256, 0, stream>>>(logits, partial);
  k_hover<<<1, 1024, 0, stream>>>(partial, hover);
  if (pre) {
    k_pre<<<8192, 256, 0, stream>>>(logits, u1, u2, u3, u4, mxM, mnM, labels, pack);
    k_sim_lds<<<8, 64, 0, stream>>>(pack, labels, hover, bsum);
  } else {
    k_sim_fb<<<8, 64, 0, stream>>>(logits, u1, u2, u3, u4, mxM, mnM, labels, hover, bsum);
  }
  k_final<<<1, 512, 0, stream>>>(bsum, out);
}